// Round 1
// baseline (1618.261 us; speedup 1.0000x reference)
//
#include <hip/hip_runtime.h>

// Problem constants
#define BB   16
#define JJ   32
#define HH   512
#define WW   512
#define KK   9
#define PAD  3
#define OH   510
#define OW   510

// Tile config
#define TILE_W 256   // output cols per block
#define TILE_H 8     // output rows per block
#define NC     8     // channels per block
#define PXT    8     // pixels per thread along x

#define IN_ROWS (TILE_H + KK - 1)   // 16
#define IN_COLS (TILE_W + KK - 1)   // 264
#define IN_STRIDE 268               // floats; 268*4=1072 bytes, 16B multiple

__global__ __launch_bounds__(256)
void conv_groups_kernel(const float* __restrict__ in,
                        const float* __restrict__ wgt,
                        float* __restrict__ out) {
    // input tile: 16*268*4 = 17152 B ; weights: 8*9*12*4 = 3456 B
    __shared__ __align__(16) float lds_in[IN_ROWS * IN_STRIDE];
    __shared__ __align__(16) float lds_w[NC * KK * 12];

    const int tid = threadIdx.x;
    const int tx  = tid & 31;   // 0..31
    const int ty  = tid >> 5;   // 0..7

    const int xt = blockIdx.x;  // 0..1
    const int yt = blockIdx.y;  // 0..63
    const int bz = blockIdx.z;  // 0..63
    const int bi = bz >> 2;     // batch 0..15
    const int cg = bz & 3;      // channel group 0..3

    const int y0  = yt * TILE_H;
    const int x0t = xt * TILE_W;

    // ---- load input tile (rows y0-3 .. y0+12, cols x0t-3 .. x0t+260) ----
    const float* inB = in + bi * (HH * WW);
    for (int r = 0; r < IN_ROWS; ++r) {
        const int gr = y0 - PAD + r;
        const bool rok = ((unsigned)gr < (unsigned)HH);
        for (int cc = tid; cc < IN_COLS; cc += 256) {
            const int gc = x0t - PAD + cc;
            float v = 0.f;
            if (rok && ((unsigned)gc < (unsigned)WW)) v = inB[gr * WW + gc];
            lds_in[r * IN_STRIDE + cc] = v;
        }
    }

    // ---- load weights for this block's 8 channels, rows padded 9->12 ----
    const float* wB = wgt + (bi * JJ + cg * NC) * (KK * KK);
    for (int idx = tid; idx < NC * KK * 12; idx += 256) {
        const int c   = idx / (KK * 12);
        const int rem = idx - c * (KK * 12);
        const int u   = rem / 12;
        const int v   = rem - u * 12;
        lds_w[idx] = (v < KK) ? wB[c * (KK * KK) + u * KK + v] : 0.f;
    }
    __syncthreads();

    // ---- compute: 8 channels x 8 px per thread ----
    float acc[NC][PXT];
    #pragma unroll
    for (int c = 0; c < NC; ++c)
        #pragma unroll
        for (int p = 0; p < PXT; ++p) acc[c][p] = 0.f;

    #pragma unroll 1
    for (int u = 0; u < KK; ++u) {
        const float4* rp = (const float4*)&lds_in[(ty + u) * IN_STRIDE + tx * PXT];
        const float4 r0 = rp[0], r1 = rp[1], r2 = rp[2], r3 = rp[3];
        const float in_row[16] = {r0.x, r0.y, r0.z, r0.w,
                                  r1.x, r1.y, r1.z, r1.w,
                                  r2.x, r2.y, r2.z, r2.w,
                                  r3.x, r3.y, r3.z, r3.w};
        #pragma unroll 1
        for (int c = 0; c < NC; ++c) {
            const float4* wp = (const float4*)&lds_w[(c * KK + u) * 12];
            const float4 w0 = wp[0], w1 = wp[1], w2 = wp[2];
            const float wv[9] = {w0.x, w0.y, w0.z, w0.w,
                                 w1.x, w1.y, w1.z, w1.w, w2.x};
            #pragma unroll
            for (int v = 0; v < KK; ++v)
                #pragma unroll
                for (int p = 0; p < PXT; ++p)
                    acc[c][p] = fmaf(wv[v], in_row[v + p], acc[c][p]);
        }
    }

    // ---- store via LDS transpose for coalesced global writes ----
    float* lds_out = lds_in;  // reuse: 8*256 floats <= 16*268
    const int Yb = y0 + ty;
    const int jbase = bi * JJ + cg * NC;

    for (int c = 0; c < NC; ++c) {
        __syncthreads();
        #pragma unroll
        for (int p = 0; p < PXT; ++p)
            lds_out[ty * 256 + tx * PXT + p] = acc[c][p];
        __syncthreads();
        if (Yb < OH) {
            float* op = out + ((size_t)(jbase + c) * OH + Yb) * OW + x0t;
            #pragma unroll
            for (int k = 0; k < 8; ++k) {
                const int X = tx + 32 * k;
                if (x0t + X < OW) op[X] = lds_out[ty * 256 + X];
            }
        }
    }
}

extern "C" void kernel_launch(void* const* d_in, const int* in_sizes, int n_in,
                              void* d_out, int out_size, void* d_ws, size_t ws_size,
                              hipStream_t stream) {
    const float* inp = (const float*)d_in[0];   // [16,1,512,512] f32
    const float* wgt = (const float*)d_in[1];   // [16,32,9,9]    f32
    float* out = (float*)d_out;                 // [16,32,510,510] f32

    dim3 grid(2, 64, 64);  // x-tiles, y-tiles, batch*channel-group
    conv_groups_kernel<<<grid, 256, 0, stream>>>(inp, wgt, out);
}

// Round 2
// 334.167 us; speedup vs baseline: 4.8427x; 4.8427x over previous
//
#include <hip/hip_runtime.h>

// Problem constants
#define BB   16
#define JJ   32
#define HH   512
#define WW   512
#define KK   9
#define PAD  3
#define OH   510
#define OW   510

// Tile config
#define TILE_W 256   // output cols per block
#define TILE_H 8     // output rows per block
#define NC     8     // channels per block
#define PXT    8     // pixels per thread along x

#define IN_ROWS (TILE_H + KK - 1)   // 16
#define IN_COLS (TILE_W + KK - 1)   // 264
#define IN_STRIDE 268               // floats; 268*4=1072 B, 16B multiple

__global__ __launch_bounds__(256)
void conv_groups_kernel(const float* __restrict__ in,
                        const float* __restrict__ wgt,
                        float* __restrict__ out) {
    __shared__ __align__(16) float lds_in[IN_ROWS * IN_STRIDE];  // 17152 B

    const int tid = threadIdx.x;
    const int tx  = tid & 31;   // 0..31
    const int ty  = tid >> 5;   // 0..7

    const int xt = blockIdx.x;  // 0..1
    const int yt = blockIdx.y;  // 0..63
    const int bz = blockIdx.z;  // 0..63
    const int bi = bz >> 2;     // batch
    const int cg = bz & 3;      // channel group

    const int y0  = yt * TILE_H;
    const int x0t = xt * TILE_W;

    // ---- stage input tile in LDS (coalesced) ----
    const float* inB = in + bi * (HH * WW);
    for (int r = 0; r < IN_ROWS; ++r) {
        const int gr = y0 - PAD + r;
        const bool rok = ((unsigned)gr < (unsigned)HH);
        for (int cc = tid; cc < IN_COLS; cc += 256) {
            const int gc = x0t - PAD + cc;
            float v = 0.f;
            if (rok && ((unsigned)gc < (unsigned)WW)) v = inB[gr * WW + gc];
            lds_in[r * IN_STRIDE + cc] = v;
        }
    }
    __syncthreads();

    // ---- accumulators: ALL indices compile-time (rule #20) ----
    float acc[NC][PXT];
    #pragma unroll
    for (int c = 0; c < NC; ++c)
        #pragma unroll
        for (int p = 0; p < PXT; ++p) acc[c][p] = 0.f;

    // weights: block-uniform address -> compiler scalarizes to s_load
    const float* wB = wgt + (bi * JJ + cg * NC) * (KK * KK);

    #pragma unroll 1
    for (int u = 0; u < KK; ++u) {
        const float4* rp = (const float4*)&lds_in[(ty + u) * IN_STRIDE + tx * PXT];
        const float4 r0 = rp[0], r1 = rp[1], r2 = rp[2], r3 = rp[3];
        const float in_row[16] = {r0.x, r0.y, r0.z, r0.w,
                                  r1.x, r1.y, r1.z, r1.w,
                                  r2.x, r2.y, r2.z, r2.w,
                                  r3.x, r3.y, r3.z, r3.w};
        #pragma unroll
        for (int c = 0; c < NC; ++c) {
            float wv[9];
            #pragma unroll
            for (int v = 0; v < KK; ++v)
                wv[v] = wB[c * (KK * KK) + u * KK + v];   // uniform -> SGPR
            #pragma unroll
            for (int v = 0; v < KK; ++v)
                #pragma unroll
                for (int p = 0; p < PXT; ++p)
                    acc[c][p] = fmaf(wv[v], in_row[v + p], acc[c][p]);
        }
    }

    // ---- store via LDS transpose for coalesced global writes ----
    float* lds_out = lds_in;  // reuse (2048 floats needed, 4288 available)
    const int Yb = y0 + ty;
    const int jbase = bi * JJ + cg * NC;

    #pragma unroll
    for (int c = 0; c < NC; ++c) {          // fully unrolled: acc[c][*] static
        __syncthreads();
        #pragma unroll
        for (int p = 0; p < PXT; ++p)
            lds_out[ty * 256 + tx * PXT + p] = acc[c][p];
        __syncthreads();
        if (Yb < OH) {
            float* op = out + ((size_t)(jbase + c) * OH + Yb) * OW + x0t;
            #pragma unroll
            for (int k = 0; k < 8; ++k) {
                const int X = tx + 32 * k;
                if (x0t + X < OW) op[X] = lds_out[ty * 256 + X];
            }
        }
    }
}

extern "C" void kernel_launch(void* const* d_in, const int* in_sizes, int n_in,
                              void* d_out, int out_size, void* d_ws, size_t ws_size,
                              hipStream_t stream) {
    const float* inp = (const float*)d_in[0];   // [16,1,512,512] f32
    const float* wgt = (const float*)d_in[1];   // [16,32,9,9]    f32
    float* out = (float*)d_out;                 // [16,32,510,510] f32

    dim3 grid(2, 64, 64);  // x-tiles, y-tiles, batch*channel-group
    conv_groups_kernel<<<grid, 256, 0, stream>>>(inp, wgt, out);
}

// Round 3
// 300.047 us; speedup vs baseline: 5.3934x; 1.1137x over previous
//
#include <hip/hip_runtime.h>

// Problem constants
#define BB   16
#define JJ   32
#define HH   512
#define WW   512
#define KK   9
#define PAD  3
#define OH   510
#define OW   510

// Tile config: 256 output cols x 8 rows x 8 channels per block.
// Each thread owns TWO 4-pixel quads: [tx*4 .. tx*4+3] and [128+tx*4 ..].
// Lane l reads LDS at byte 16*l -> conflict-free b128 (optimal pattern),
// and global stores are directly coalesced -> no LDS transpose needed.
#define TILE_W 256
#define TILE_H 8
#define NC     8

#define IN_ROWS (TILE_H + KK - 1)   // 16
#define IN_COLS (TILE_W + KK - 1)   // 264
#define IN_STRIDE 268               // 1072 B, 16B multiple

__global__ __launch_bounds__(256)
void conv_groups_kernel(const float* __restrict__ in,
                        const float* __restrict__ wgt,
                        float* __restrict__ out) {
    __shared__ __align__(16) float lds_in[IN_ROWS * IN_STRIDE];  // 17152 B

    const int tid = threadIdx.x;
    const int tx  = tid & 31;   // 0..31
    const int ty  = tid >> 5;   // 0..7

    const int xt = blockIdx.x;  // 0..1
    const int yt = blockIdx.y;  // 0..63
    const int bz = blockIdx.z;  // 0..63
    const int bi = bz >> 2;     // batch
    const int cg = bz & 3;      // channel group

    const int y0  = yt * TILE_H;
    const int x0t = xt * TILE_W;

    // ---- stage input tile in LDS (coalesced, zero-padded halo) ----
    const float* inB = in + bi * (HH * WW);
    for (int r = 0; r < IN_ROWS; ++r) {
        const int gr = y0 - PAD + r;
        const bool rok = ((unsigned)gr < (unsigned)HH);
        for (int cc = tid; cc < IN_COLS; cc += 256) {
            const int gc = x0t - PAD + cc;
            float v = 0.f;
            if (rok && ((unsigned)gc < (unsigned)WW)) v = inB[gr * WW + gc];
            lds_in[r * IN_STRIDE + cc] = v;
        }
    }
    __syncthreads();

    // ---- accumulators: all indices compile-time ----
    float acc[NC][2][4];
    #pragma unroll
    for (int c = 0; c < NC; ++c)
        #pragma unroll
        for (int q = 0; q < 2; ++q)
            #pragma unroll
            for (int p = 0; p < 4; ++p) acc[c][q][p] = 0.f;

    // weights: block-uniform -> s_load broadcast
    const float* wB = wgt + (bi * JJ + cg * NC) * (KK * KK);

    #pragma unroll 1
    for (int u = 0; u < KK; ++u) {
        // 12-float sliding windows for each quad, conflict-free b128 reads
        const float4* rp0 = (const float4*)&lds_in[(ty + u) * IN_STRIDE + tx * 4];
        const float4 a0 = rp0[0], a1 = rp0[1], a2 = rp0[2];
        const float4* rp1 = (const float4*)&lds_in[(ty + u) * IN_STRIDE + 128 + tx * 4];
        const float4 b0 = rp1[0], b1 = rp1[1], b2 = rp1[2];
        const float w0[12] = {a0.x, a0.y, a0.z, a0.w,
                              a1.x, a1.y, a1.z, a1.w,
                              a2.x, a2.y, a2.z, a2.w};
        const float w1[12] = {b0.x, b0.y, b0.z, b0.w,
                              b1.x, b1.y, b1.z, b1.w,
                              b2.x, b2.y, b2.z, b2.w};

        #pragma unroll
        for (int c = 0; c < NC; ++c) {
            float wv[9];
            #pragma unroll
            for (int v = 0; v < KK; ++v)
                wv[v] = wB[c * (KK * KK) + u * KK + v];   // uniform -> SGPR
            #pragma unroll
            for (int v = 0; v < KK; ++v) {
                #pragma unroll
                for (int p = 0; p < 4; ++p) {
                    acc[c][0][p] = fmaf(wv[v], w0[v + p], acc[c][0][p]);
                    acc[c][1][p] = fmaf(wv[v], w1[v + p], acc[c][1][p]);
                }
            }
        }
    }

    // ---- direct coalesced global stores (no transpose, no barriers) ----
    const int Yb = y0 + ty;
    const int jbase = bi * JJ + cg * NC;
    if (Yb < OH) {
        #pragma unroll
        for (int c = 0; c < NC; ++c) {
            float* op = out + ((size_t)(jbase + c) * OH + Yb) * OW;
            #pragma unroll
            for (int q = 0; q < 2; ++q) {
                const int X = x0t + q * 128 + tx * 4;
                if (X + 3 < OW) {
                    // row base only 8B-aligned (OW=510) -> use float2 pairs
                    *(float2*)(op + X)     = make_float2(acc[c][q][0], acc[c][q][1]);
                    *(float2*)(op + X + 2) = make_float2(acc[c][q][2], acc[c][q][3]);
                } else {
                    #pragma unroll
                    for (int p = 0; p < 4; ++p)
                        if (X + p < OW) op[X + p] = acc[c][q][p];
                }
            }
        }
    }
}

extern "C" void kernel_launch(void* const* d_in, const int* in_sizes, int n_in,
                              void* d_out, int out_size, void* d_ws, size_t ws_size,
                              hipStream_t stream) {
    const float* inp = (const float*)d_in[0];   // [16,1,512,512] f32
    const float* wgt = (const float*)d_in[1];   // [16,32,9,9]    f32
    float* out = (float*)d_out;                 // [16,32,510,510] f32

    dim3 grid(2, 64, 64);  // x-tiles, y-tiles, batch*channel-group
    conv_groups_kernel<<<grid, 256, 0, stream>>>(inp, wgt, out);
}

// Round 4
// 271.233 us; speedup vs baseline: 5.9663x; 1.1062x over previous
//
#include <hip/hip_runtime.h>

// Problem constants
#define BB  16
#define JJ  32
#define HH  512
#define WW  512
#define KK  9
#define PAD 3
#define OH  510
#define OW  510

// Implicit-GEMM tiling: per block = one batch, one output row, 128 pixels.
// O[32 j][128 n] = W[32][K96] x im2col[K96][128 n], K slots k = u*10 + v
// (81 taps, slots 89..95 zero), 3 MFMA K-slices of 32.
#define NPIX 128
#define KSLOT 104                 // padded k slots per row (bank stagger)
#define ROWB (KSLOT * 2)          // 208 bytes per row (16B multiple)
#define W_BASE (NPIX * ROWB)      // 26624
#define LDS_BYTES (W_BASE + JJ * ROWB)  // 33280

typedef __bf16 bf16x8 __attribute__((ext_vector_type(8)));
typedef float  f32x4  __attribute__((ext_vector_type(4)));

// round-half-up f32->bf16, packed pair (lo=a, hi=b)
__device__ __forceinline__ unsigned pack2bf(float a, float b) {
    unsigned ua = __float_as_uint(a) + 0x8000u;
    unsigned ub = __float_as_uint(b) + 0x8000u;
    return (ua >> 16) | (ub & 0xFFFF0000u);
}

// XOR swizzle: spreads the 8-row bank period; bijective because
// 8 rows * 208 B = 1664 = 26 * 64 (64B blocks never straddle a swizzle change)
__device__ __forceinline__ unsigned swz_of(int row) {
    return (((unsigned)row >> 3) & 3u) << 4;
}

__global__ __launch_bounds__(256, 4)
void conv_mfma_kernel(const float* __restrict__ in,
                      const float* __restrict__ wgt,
                      float* __restrict__ out) {
    __shared__ __align__(16) char lds[LDS_BYTES];

    const int tid = threadIdx.x;
    const int xt  = blockIdx.x;   // 0..3
    const int y   = blockIdx.y;   // 0..509
    const int bi  = blockIdx.z;   // 0..15
    const int x0  = xt * NPIX;

    // ---- zero k-slots 90..103 (bytes 180..207) of im2col and weight rows ----
    for (int idx = tid; idx < NPIX * 7; idx += 256) {
        const int n = idx / 7, z = idx % 7;
        *(unsigned*)(lds + ((n * ROWB + 180 + 4 * z) ^ swz_of(n))) = 0u;
    }
    for (int idx = tid; idx < JJ * 7; idx += 256) {
        const int j = idx / 7, z = idx % 7;
        *(unsigned*)(lds + ((W_BASE + j * ROWB + 180 + 4 * z) ^ swz_of(j))) = 0u;
    }

    // ---- stage weights: unit = (j, u): 9 f32 -> 5 packed b32 ----
    const float* wB = wgt + (size_t)(bi * JJ) * (KK * KK);
    for (int idx = tid; idx < JJ * KK; idx += 256) {
        const int j = idx / KK, u = idx % KK;
        const float* wr = wB + j * (KK * KK) + u * KK;
        float w[9];
        #pragma unroll
        for (int v = 0; v < 9; ++v) w[v] = wr[v];
        const int base = W_BASE + j * ROWB + u * 20;
        const unsigned s = swz_of(j);
        *(unsigned*)(lds + ((base +  0) ^ s)) = pack2bf(w[0], w[1]);
        *(unsigned*)(lds + ((base +  4) ^ s)) = pack2bf(w[2], w[3]);
        *(unsigned*)(lds + ((base +  8) ^ s)) = pack2bf(w[4], w[5]);
        *(unsigned*)(lds + ((base + 12) ^ s)) = pack2bf(w[6], w[7]);
        *(unsigned*)(lds + ((base + 16) ^ s)) = pack2bf(w[8], 0.f);
    }

    // ---- im2col construction: unit = (u, n): 9 guarded f32 -> 5 b32 ----
    const float* inB = in + (size_t)bi * (HH * WW);
    #pragma unroll 1
    for (int it = 0; it < 5; ++it) {
        const int idx = tid + it * 256;
        if (idx < KK * NPIX) {
            const int u = idx >> 7, n = idx & 127;
            const int gr = y - PAD + u;
            const int c0 = x0 + n - PAD;
            float vv[9];
            #pragma unroll
            for (int v = 0; v < 9; ++v) vv[v] = 0.f;
            if ((unsigned)gr < (unsigned)HH) {
                const float* rp = inB + gr * WW + c0;
                if (c0 >= 0 && c0 + 9 <= WW) {
                    #pragma unroll
                    for (int v = 0; v < 9; ++v) vv[v] = rp[v];
                } else {
                    #pragma unroll
                    for (int v = 0; v < 9; ++v)
                        if ((unsigned)(c0 + v) < (unsigned)WW) vv[v] = rp[v];
                }
            }
            const int base = n * ROWB + u * 20;
            const unsigned s = swz_of(n);
            *(unsigned*)(lds + ((base +  0) ^ s)) = pack2bf(vv[0], vv[1]);
            *(unsigned*)(lds + ((base +  4) ^ s)) = pack2bf(vv[2], vv[3]);
            *(unsigned*)(lds + ((base +  8) ^ s)) = pack2bf(vv[4], vv[5]);
            *(unsigned*)(lds + ((base + 12) ^ s)) = pack2bf(vv[6], vv[7]);
            *(unsigned*)(lds + ((base + 16) ^ s)) = pack2bf(vv[8], 0.f);
        }
    }
    __syncthreads();

    // ---- MFMA: wave w owns n-subtiles {2w, 2w+1}; both m-tiles (j 0..31) ----
    const int lane = tid & 63;
    const int w    = tid >> 6;
    const int col  = lane & 15;
    const int q    = lane >> 4;       // k-chunk / D-row group
    const int n0   = w * 32;

    f32x4 acc00 = {0.f, 0.f, 0.f, 0.f};
    f32x4 acc01 = {0.f, 0.f, 0.f, 0.f};
    f32x4 acc10 = {0.f, 0.f, 0.f, 0.f};
    f32x4 acc11 = {0.f, 0.f, 0.f, 0.f};

    const int arow0 = col, arow1 = 16 + col;
    const int bcol0 = n0 + col, bcol1 = n0 + 16 + col;
    const unsigned sa0 = swz_of(arow0), sa1 = swz_of(arow1);
    const unsigned sb0 = swz_of(bcol0), sb1 = swz_of(bcol1);

    #pragma unroll
    for (int s = 0; s < 3; ++s) {
        const int ko = s * 64 + q * 16;
        bf16x8 a0 = *(const bf16x8*)(lds + ((W_BASE + arow0 * ROWB + ko) ^ sa0));
        bf16x8 a1 = *(const bf16x8*)(lds + ((W_BASE + arow1 * ROWB + ko) ^ sa1));
        bf16x8 b0 = *(const bf16x8*)(lds + ((bcol0 * ROWB + ko) ^ sb0));
        bf16x8 b1 = *(const bf16x8*)(lds + ((bcol1 * ROWB + ko) ^ sb1));
        acc00 = __builtin_amdgcn_mfma_f32_16x16x32_bf16(a0, b0, acc00, 0, 0, 0);
        acc01 = __builtin_amdgcn_mfma_f32_16x16x32_bf16(a0, b1, acc01, 0, 0, 0);
        acc10 = __builtin_amdgcn_mfma_f32_16x16x32_bf16(a1, b0, acc10, 0, 0, 0);
        acc11 = __builtin_amdgcn_mfma_f32_16x16x32_bf16(a1, b1, acc11, 0, 0, 0);
    }

    // ---- store: D row = q*4 + r (j-dim), col = lane&15 (pixel) ----
    const size_t plane = (size_t)OH * OW;
    float* outB = out + (size_t)(bi * JJ) * plane + (size_t)y * OW;
    const int xc0 = x0 + n0 + col;
    const int xc1 = x0 + n0 + 16 + col;

    #pragma unroll
    for (int r = 0; r < 4; ++r) {
        const int j0 = q * 4 + r;        // m=0 tile
        const int j1 = 16 + q * 4 + r;   // m=1 tile
        if (xc0 < OW) {
            outB[(size_t)j0 * plane + xc0] = acc00[r];
            outB[(size_t)j1 * plane + xc0] = acc10[r];
        }
        if (xc1 < OW) {
            outB[(size_t)j0 * plane + xc1] = acc01[r];
            outB[(size_t)j1 * plane + xc1] = acc11[r];
        }
    }
}

extern "C" void kernel_launch(void* const* d_in, const int* in_sizes, int n_in,
                              void* d_out, int out_size, void* d_ws, size_t ws_size,
                              hipStream_t stream) {
    const float* inp = (const float*)d_in[0];   // [16,1,512,512] f32
    const float* wgt = (const float*)d_in[1];   // [16,32,9,9]    f32
    float* out = (float*)d_out;                 // [16,32,510,510] f32

    dim3 grid(4, OH, BB);   // 4 x-tiles of 128 px, 510 rows, 16 batches
    conv_mfma_kernel<<<grid, 256, 0, stream>>>(inp, wgt, out);
}

// Round 5
// 244.618 us; speedup vs baseline: 6.6155x; 1.1088x over previous
//
#include <hip/hip_runtime.h>

// Problem constants
#define BB  16
#define JJ  32
#define HH  512
#define WW  512
#define KK  9
#define PAD 3
#define OH  510
#define OW  510

// No-im2col implicit GEMM: k = u*16 + v (u=0..8 taps rows, v padded to 16).
// B-fragment (8 contiguous k, fixed pixel n) == 8 contiguous raw input
// elements -> read directly from LDS raw rows stored as 8 shifted copies
// (copy c: elements c+8m.. as aligned 16B chunks -> single ds_read_b128).
// Slots v>=9: A=0, B=real finite data -> exact 0 contribution.
#define NPIX   128                 // pixels per block
#define RROWS  8                   // output rows per block
#define NRAW   16                  // raw input rows staged (RROWS+KK-1)
#define NCHUNK 17                  // 16B chunks per copy (frag starts e<=135)
#define COPY_PITCH 272             // 17*16 B; mod 128 = 16 -> copies bank-distinct
#define ROW_PITCH  2192            // 8*272 + 16 pad; mod 128 = 16 (break row alias)
#define LDS_BYTES (NRAW * ROW_PITCH)  // 35072

typedef __bf16 bf16x8 __attribute__((ext_vector_type(8)));
typedef float  f32x4  __attribute__((ext_vector_type(4)));

// round-half-up f32->bf16 (same numerics as validated round-4 kernel)
__device__ __forceinline__ unsigned pack2bf(float a, float b) {
    unsigned ua = __float_as_uint(a) + 0x8000u;
    unsigned ub = __float_as_uint(b) + 0x8000u;
    return (ua >> 16) | (ub & 0xFFFF0000u);
}
__device__ __forceinline__ __bf16 tobf(float f) {
    unsigned short us = (unsigned short)((__float_as_uint(f) + 0x8000u) >> 16);
    return __builtin_bit_cast(__bf16, us);
}

__global__ __launch_bounds__(256, 4)
void conv_mfma_kernel(const float* __restrict__ in,
                      const float* __restrict__ wgt,
                      float* __restrict__ out) {
    __shared__ __align__(16) char lds[LDS_BYTES];

    const int tid  = threadIdx.x;
    const int lane = tid & 63;
    const int w    = tid >> 6;     // wave 0..3 -> n-subtile base
    const int col  = lane & 15;
    const int q    = lane >> 4;

    const int x0 = blockIdx.x * NPIX;
    const int y0 = blockIdx.y * RROWS;
    const int bi = blockIdx.z;

    // ---- A fragments (weights) straight into registers, once per block ----
    // afrag[s][mt]: lane holds W[mt*16+col][u=2s+(q>>1)][v0+(0..7)], v>=9 -> 0
    const float* wB = wgt + (size_t)bi * JJ * (KK * KK);
    bf16x8 afrag[5][2];
    #pragma unroll
    for (int s = 0; s < 5; ++s) {
        const int u  = 2 * s + (q >> 1);
        const int v0 = (q & 1) * 8;
        #pragma unroll
        for (int mt = 0; mt < 2; ++mt) {
            const int j = mt * 16 + col;
            const float* wr = wB + j * (KK * KK) + u * KK;
            #pragma unroll
            for (int e = 0; e < 8; ++e) {
                const int ve = v0 + e;
                const float wv = (u <= 8 && ve <= 8) ? wr[ve] : 0.f;  // guarded load
                afrag[s][mt][e] = tobf(wv);
            }
        }
    }

    // ---- stage raw rows as 8 shifted bf16 copies ----
    // unit (rr, m): elements 8m..8m+14 -> chunk m of copies 0..7
    const float* inB = in + (size_t)bi * (HH * WW);
    #pragma unroll 1
    for (int idx = tid; idx < NRAW * NCHUNK; idx += 256) {
        const int rr = idx / NCHUNK;
        const int m  = idx - rr * NCHUNK;
        const int gr = y0 - PAD + rr;
        const int gc0 = x0 - PAD + m * 8;
        const bool rok = ((unsigned)gr < (unsigned)HH);
        float el[15];
        #pragma unroll
        for (int e = 0; e < 15; ++e) {
            const int gc = gc0 + e;
            el[e] = (rok && (unsigned)gc < (unsigned)WW) ? inB[gr * WW + gc] : 0.f;
        }
        // shared pack grids: P[i]=(el2i,el2i+1), Q[i]=(el2i+1,el2i+2)
        unsigned P[7], Q[7];
        #pragma unroll
        for (int i = 0; i < 7; ++i) {
            P[i] = pack2bf(el[2 * i],     el[2 * i + 1]);
            Q[i] = pack2bf(el[2 * i + 1], el[2 * i + 2]);
        }
        char* base = lds + rr * ROW_PITCH + m * 16;
        #pragma unroll
        for (int c = 0; c < 8; ++c) {
            uint4 val;
            if ((c & 1) == 0) val = make_uint4(P[c / 2], P[c / 2 + 1], P[c / 2 + 2], P[c / 2 + 3]);
            else              val = make_uint4(Q[c / 2], Q[c / 2 + 1], Q[c / 2 + 2], Q[c / 2 + 3]);
            *(uint4*)(base + c * COPY_PITCH) = val;
        }
    }
    __syncthreads();

    // ---- 8 output rows: B-fragments read directly (1 ds_read_b128 each) ----
    const int n0 = w * 32;
    const size_t plane = (size_t)OH * OW;
    float* outB = out + (size_t)bi * JJ * plane;

    #pragma unroll 1
    for (int r = 0; r < RROWS; ++r) {
        const int y = y0 + r;
        f32x4 acc00 = {0.f, 0.f, 0.f, 0.f};
        f32x4 acc01 = {0.f, 0.f, 0.f, 0.f};
        f32x4 acc10 = {0.f, 0.f, 0.f, 0.f};
        f32x4 acc11 = {0.f, 0.f, 0.f, 0.f};

        #pragma unroll
        for (int s = 0; s < 5; ++s) {
            int u = 2 * s + (q >> 1);
            if (u > 8) u = 0;                 // clamp: afrag==0 there, any finite B ok
            const int v0 = (q & 1) * 8;
            const int rr = r + u;
            const int e0 = n0 + col + v0;     // fragment start element, t=0
            const char* p0 = lds + rr * ROW_PITCH
                           + (e0 & 7) * COPY_PITCH + ((e0 >> 3) << 4);
            const bf16x8 b0 = *(const bf16x8*)p0;
            const bf16x8 b1 = *(const bf16x8*)(p0 + 32);   // e0+16: same copy, +2 chunks
            acc00 = __builtin_amdgcn_mfma_f32_16x16x32_bf16(afrag[s][0], b0, acc00, 0, 0, 0);
            acc01 = __builtin_amdgcn_mfma_f32_16x16x32_bf16(afrag[s][0], b1, acc01, 0, 0, 0);
            acc10 = __builtin_amdgcn_mfma_f32_16x16x32_bf16(afrag[s][1], b0, acc10, 0, 0, 0);
            acc11 = __builtin_amdgcn_mfma_f32_16x16x32_bf16(afrag[s][1], b1, acc11, 0, 0, 0);
        }

        if (y < OH) {
            float* orow = outB + (size_t)y * OW;
            const int xc0 = x0 + n0 + col;
            const int xc1 = xc0 + 16;
            #pragma unroll
            for (int rg = 0; rg < 4; ++rg) {
                const int j0 = q * 4 + rg;
                const int j1 = 16 + q * 4 + rg;
                if (xc0 < OW) {
                    orow[(size_t)j0 * plane + xc0] = acc00[rg];
                    orow[(size_t)j1 * plane + xc0] = acc10[rg];
                }
                if (xc1 < OW) {
                    orow[(size_t)j0 * plane + xc1] = acc01[rg];
                    orow[(size_t)j1 * plane + xc1] = acc11[rg];
                }
            }
        }
    }
}

extern "C" void kernel_launch(void* const* d_in, const int* in_sizes, int n_in,
                              void* d_out, int out_size, void* d_ws, size_t ws_size,
                              hipStream_t stream) {
    const float* inp = (const float*)d_in[0];   // [16,1,512,512] f32
    const float* wgt = (const float*)d_in[1];   // [16,32,9,9]    f32
    float* out = (float*)d_out;                 // [16,32,510,510] f32

    dim3 grid(4, 64, BB);   // 4 x-tiles x 64 row-tiles x 16 batches = 4096 blocks
    conv_mfma_kernel<<<grid, 256, 0, stream>>>(inp, wgt, out);
}

// Round 6
// 223.128 us; speedup vs baseline: 7.2526x; 1.0963x over previous
//
#include <hip/hip_runtime.h>

// Problem constants
#define BB  16
#define JJ  32
#define HH  512
#define WW  512
#define KK  9
#define PAD 3
#define OH  510
#define OW  510

// No-im2col implicit GEMM: k = u*16 + v (u=0..8 tap rows, v padded to 16).
// B-fragment (8 contiguous k, fixed pixel n) == 8 contiguous raw input
// elements -> read directly from LDS raw rows stored as 8 shifted copies.
// Weights: staged via LDS (coalesced fill of padded [32][10][16] f32 region,
// then 2x float4 LDS reads + pack per fragment) -- replaces 80 scattered
// global loads + 160 cvt per thread (round-5's dominant cost).
#define NPIX   128
#define RROWS  8
#define NRAW   16
#define NCHUNK 17
#define COPY_PITCH 272             // 17*16 B; mod 128 = 16
#define ROW_PITCH  2192            // 8*272 + 16 pad
#define LDS_BYTES (NRAW * ROW_PITCH)  // 35072

// padded raw-weight region (union with input tile region)
#define WJ_PITCH 656               // 10*64 + 16 pad; /4 mod 32 = 4-bank stagger
#define W_RAW_BYTES (JJ * WJ_PITCH)   // 20992 <= LDS_BYTES

typedef __bf16 bf16x8 __attribute__((ext_vector_type(8)));
typedef float  f32x4  __attribute__((ext_vector_type(4)));

__device__ __forceinline__ unsigned pack2bf(float a, float b) {
    unsigned ua = __float_as_uint(a) + 0x8000u;
    unsigned ub = __float_as_uint(b) + 0x8000u;
    return (ua >> 16) | (ub & 0xFFFF0000u);
}

__global__ __launch_bounds__(256, 4)
void conv_mfma_kernel(const float* __restrict__ in,
                      const float* __restrict__ wgt,
                      float* __restrict__ out) {
    __shared__ __align__(16) char lds[LDS_BYTES];

    const int tid  = threadIdx.x;
    const int lane = tid & 63;
    const int w    = tid >> 6;
    const int col  = lane & 15;
    const int q    = lane >> 4;

    const int x0 = blockIdx.x * NPIX;
    const int y0 = blockIdx.y * RROWS;
    const int bi = blockIdx.z;

    // ---- phase W1: zero + fill padded raw weights in LDS (coalesced) ----
    {
        const uint4 z = make_uint4(0u, 0u, 0u, 0u);
        for (int idx = tid; idx < W_RAW_BYTES / 16; idx += 256)
            *(uint4*)(lds + idx * 16) = z;
    }
    __syncthreads();
    const float* wB = wgt + (size_t)bi * JJ * (KK * KK);
    {
        // 32*81 = 2592 real values; consecutive tid -> consecutive v (banks ok)
        for (int idx = tid; idx < JJ * KK * KK; idx += 256) {
            const int j   = idx / (KK * KK);
            const int rem = idx - j * (KK * KK);
            const int u   = rem / KK;
            const int v   = rem - u * KK;
            *(float*)(lds + j * WJ_PITCH + u * 64 + v * 4) = wB[idx];
        }
    }
    __syncthreads();

    // ---- phase W2: assemble A fragments into registers ----
    // afrag[s][mt]: lane holds W[mt*16+col][u=2s+(q>>1)][v0..v0+7], v0=(q&1)*8
    bf16x8 afrag[5][2];
    #pragma unroll
    for (int s = 0; s < 5; ++s) {
        const int u = 2 * s + (q >> 1);          // 0..9 (u=9 row is zeros)
        #pragma unroll
        for (int mt = 0; mt < 2; ++mt) {
            const int j = mt * 16 + col;
            const char* p = lds + j * WJ_PITCH + u * 64 + (q & 1) * 32;
            const float4 fa = *(const float4*)p;
            const float4 fb = *(const float4*)(p + 16);
            const uint4 pk = make_uint4(pack2bf(fa.x, fa.y), pack2bf(fa.z, fa.w),
                                        pack2bf(fb.x, fb.y), pack2bf(fb.z, fb.w));
            afrag[s][mt] = __builtin_bit_cast(bf16x8, pk);
        }
    }
    __syncthreads();   // done with weight region; input staging reuses it

    // ---- stage raw input rows as 8 shifted bf16 copies ----
    const float* inB = in + (size_t)bi * (HH * WW);
    #pragma unroll 1
    for (int idx = tid; idx < NRAW * NCHUNK; idx += 256) {
        const int rr = idx / NCHUNK;
        const int m  = idx - rr * NCHUNK;
        const int gr = y0 - PAD + rr;
        const int gc0 = x0 - PAD + m * 8;
        const bool rok = ((unsigned)gr < (unsigned)HH);
        float el[15];
        #pragma unroll
        for (int e = 0; e < 15; ++e) {
            const int gc = gc0 + e;
            el[e] = (rok && (unsigned)gc < (unsigned)WW) ? inB[gr * WW + gc] : 0.f;
        }
        unsigned P[7], Q[7];
        #pragma unroll
        for (int i = 0; i < 7; ++i) {
            P[i] = pack2bf(el[2 * i],     el[2 * i + 1]);
            Q[i] = pack2bf(el[2 * i + 1], el[2 * i + 2]);
        }
        char* base = lds + rr * ROW_PITCH + m * 16;
        #pragma unroll
        for (int c = 0; c < 8; ++c) {
            uint4 val;
            if ((c & 1) == 0) val = make_uint4(P[c / 2], P[c / 2 + 1], P[c / 2 + 2], P[c / 2 + 3]);
            else              val = make_uint4(Q[c / 2], Q[c / 2 + 1], Q[c / 2 + 2], Q[c / 2 + 3]);
            *(uint4*)(base + c * COPY_PITCH) = val;
        }
    }
    __syncthreads();

    // ---- 8 output rows: B-fragments read directly (1 ds_read_b128 each) ----
    const int n0 = w * 32;
    const size_t plane = (size_t)OH * OW;
    float* outB = out + (size_t)bi * JJ * plane;

    #pragma unroll 1
    for (int r = 0; r < RROWS; ++r) {
        const int y = y0 + r;
        f32x4 acc00 = {0.f, 0.f, 0.f, 0.f};
        f32x4 acc01 = {0.f, 0.f, 0.f, 0.f};
        f32x4 acc10 = {0.f, 0.f, 0.f, 0.f};
        f32x4 acc11 = {0.f, 0.f, 0.f, 0.f};

        #pragma unroll
        for (int s = 0; s < 5; ++s) {
            int u = 2 * s + (q >> 1);
            if (u > 8) u = 0;                 // afrag==0 there; any finite B ok
            const int v0 = (q & 1) * 8;
            const int rr = r + u;
            const int e0 = n0 + col + v0;
            const char* p0 = lds + rr * ROW_PITCH
                           + (e0 & 7) * COPY_PITCH + ((e0 >> 3) << 4);
            const bf16x8 b0 = *(const bf16x8*)p0;
            const bf16x8 b1 = *(const bf16x8*)(p0 + 32);
            acc00 = __builtin_amdgcn_mfma_f32_16x16x32_bf16(afrag[s][0], b0, acc00, 0, 0, 0);
            acc01 = __builtin_amdgcn_mfma_f32_16x16x32_bf16(afrag[s][0], b1, acc01, 0, 0, 0);
            acc10 = __builtin_amdgcn_mfma_f32_16x16x32_bf16(afrag[s][1], b0, acc10, 0, 0, 0);
            acc11 = __builtin_amdgcn_mfma_f32_16x16x32_bf16(afrag[s][1], b1, acc11, 0, 0, 0);
        }

        if (y < OH) {
            float* orow = outB + (size_t)y * OW;
            const int xc0 = x0 + n0 + col;
            const int xc1 = xc0 + 16;
            #pragma unroll
            for (int rg = 0; rg < 4; ++rg) {
                const int j0 = q * 4 + rg;
                const int j1 = 16 + q * 4 + rg;
                if (xc0 < OW) {
                    orow[(size_t)j0 * plane + xc0] = acc00[rg];
                    orow[(size_t)j1 * plane + xc0] = acc10[rg];
                }
                if (xc1 < OW) {
                    orow[(size_t)j0 * plane + xc1] = acc01[rg];
                    orow[(size_t)j1 * plane + xc1] = acc11[rg];
                }
            }
        }
    }
}

extern "C" void kernel_launch(void* const* d_in, const int* in_sizes, int n_in,
                              void* d_out, int out_size, void* d_ws, size_t ws_size,
                              hipStream_t stream) {
    const float* inp = (const float*)d_in[0];   // [16,1,512,512] f32
    const float* wgt = (const float*)d_in[1];   // [16,32,9,9]    f32
    float* out = (float*)d_out;                 // [16,32,510,510] f32

    dim3 grid(4, 64, BB);
    conv_mfma_kernel<<<grid, 256, 0, stream>>>(inp, wgt, out);
}